// Round 1
// baseline (287.531 us; speedup 1.0000x reference)
//
#include <hip/hip_runtime.h>

#define NB 4
#define NS 2048
#define ND 768
#define NH 12
#define NDH 64
#define PITCH 72
#define LOG2E 1.44269504088896340736f
#define SSCALE (0.125f * LOG2E)   // 1/sqrt(64) * log2(e), softmax in base-2

typedef __bf16 bf16x8 __attribute__((ext_vector_type(8)));
typedef __bf16 bf16x4 __attribute__((ext_vector_type(4)));
typedef float  f32x4  __attribute__((ext_vector_type(4)));

#define MFMA16(a, b, c) __builtin_amdgcn_mfma_f32_16x16x32_bf16(a, b, c, 0, 0, 0)

__device__ __forceinline__ __bf16 f2bf(float f) {
    // RNE float->bf16, no NaN path needed (all values finite here)
    unsigned u = __builtin_bit_cast(unsigned, f);
    u += 0x7fffu + ((u >> 16) & 1u);
    unsigned short s = (unsigned short)(u >> 16);
    return __builtin_bit_cast(__bf16, s);
}

__device__ __forceinline__ bf16x4 cvt4(float4 v) {
    bf16x4 o;
    o[0] = f2bf(v.x); o[1] = f2bf(v.y); o[2] = f2bf(v.z); o[3] = f2bf(v.w);
    return o;
}

// ---------------------------------------------------------------------------
// Kernel 1: per-head QKV projections.
//  Q[b,h,s,e] = sum_d x[b,s,h*64+d] * wq[h,e,d] + bq[h,e]   (bf16 out)
//  K same; V stored TRANSPOSED: Vt[b,h,e,s]  (so attn reads are contiguous)
// One block = (s-tile of 64, h, b). 4 waves; MFMA 16x16x32 bf16.
// A/B fragment layout (m89/m120-verified): A[m=lane&15][k=quad*8+j],
// B stored as [n][k] row-major reads identically. C/D: row=quad*4+reg, col=lane&15.
// ---------------------------------------------------------------------------
__global__ __launch_bounds__(256) void proj_kernel(
    const float* __restrict__ x,
    const float* __restrict__ wq, const float* __restrict__ bq,
    const float* __restrict__ wk, const float* __restrict__ bk,
    const float* __restrict__ wv, const float* __restrict__ bv,
    __bf16* __restrict__ qws, __bf16* __restrict__ kws, __bf16* __restrict__ vtws)
{
    const int st = blockIdx.x, h = blockIdx.y, b = blockIdx.z;
    const int s0 = st * 64;
    const int tid = threadIdx.x;

    __shared__ __align__(16) __bf16 Xs[64 * PITCH];
    __shared__ __align__(16) __bf16 Wqs[64 * PITCH];
    __shared__ __align__(16) __bf16 Wks[64 * PITCH];
    __shared__ __align__(16) __bf16 Wvs[64 * PITCH];

    {
        const int r  = tid >> 2;      // 0..63 row
        const int q4 = tid & 3;
        const float* xrow = x + (size_t)(b * NS + s0 + r) * ND + h * NDH;
        const float* wqr = wq + (size_t)(h * NDH + r) * NDH;
        const float* wkr = wk + (size_t)(h * NDH + r) * NDH;
        const float* wvr = wv + (size_t)(h * NDH + r) * NDH;
#pragma unroll
        for (int i = 0; i < 4; ++i) {
            const int cv = q4 * 4 + i;      // float4 index 0..15
            float4 v;
            v = *(const float4*)(xrow + cv * 4);
            *(bf16x4*)&Xs[r * PITCH + cv * 4] = cvt4(v);
            v = *(const float4*)(wqr + cv * 4);
            *(bf16x4*)&Wqs[r * PITCH + cv * 4] = cvt4(v);
            v = *(const float4*)(wkr + cv * 4);
            *(bf16x4*)&Wks[r * PITCH + cv * 4] = cvt4(v);
            v = *(const float4*)(wvr + cv * 4);
            *(bf16x4*)&Wvs[r * PITCH + cv * 4] = cvt4(v);
        }
    }
    __syncthreads();

    const int lane = tid & 63;
    const int wvid = tid >> 6;      // wave 0..3
    const int col  = lane & 15;
    const int quad = lane >> 4;

    const size_t bh = (size_t)(b * NH + h);

    // A fragments: X rows (for Q,K) and Wv rows (for Vt)
    bf16x8 xa0  = *(const bf16x8*)&Xs[(wvid * 16 + col) * PITCH + quad * 8];
    bf16x8 xa1  = *(const bf16x8*)&Xs[(wvid * 16 + col) * PITCH + 32 + quad * 8];
    bf16x8 wva0 = *(const bf16x8*)&Wvs[(wvid * 16 + col) * PITCH + quad * 8];
    bf16x8 wva1 = *(const bf16x8*)&Wvs[(wvid * 16 + col) * PITCH + 32 + quad * 8];

    // ---- Q and K: D[s_local][e], waves split s (M), n-tiles over e ----
#pragma unroll
    for (int nt = 0; nt < 4; ++nt) {
        bf16x8 bq0 = *(const bf16x8*)&Wqs[(nt * 16 + col) * PITCH + quad * 8];
        bf16x8 bq1 = *(const bf16x8*)&Wqs[(nt * 16 + col) * PITCH + 32 + quad * 8];
        bf16x8 bk0 = *(const bf16x8*)&Wks[(nt * 16 + col) * PITCH + quad * 8];
        bf16x8 bk1 = *(const bf16x8*)&Wks[(nt * 16 + col) * PITCH + 32 + quad * 8];
        f32x4 aq = {0.f, 0.f, 0.f, 0.f};
        f32x4 ak = {0.f, 0.f, 0.f, 0.f};
        aq = MFMA16(xa0, bq0, aq);
        aq = MFMA16(xa1, bq1, aq);
        ak = MFMA16(xa0, bk0, ak);
        ak = MFMA16(xa1, bk1, ak);
        const float biasq = bq[h * NDH + nt * 16 + col];
        const float biask = bk[h * NDH + nt * 16 + col];
#pragma unroll
        for (int r = 0; r < 4; ++r) {
            const int srow = s0 + wvid * 16 + quad * 4 + r;
            qws[(bh * NS + srow) * NDH + nt * 16 + col] = f2bf(aq[r] + biasq);
            kws[(bh * NS + srow) * NDH + nt * 16 + col] = f2bf(ak[r] + biask);
        }
    }

    // ---- Vt: D[e][s_local] = Wv . X^T; waves split e (M), n-tiles over s ----
#pragma unroll
    for (int nt = 0; nt < 4; ++nt) {
        bf16x8 xb0 = *(const bf16x8*)&Xs[(nt * 16 + col) * PITCH + quad * 8];
        bf16x8 xb1 = *(const bf16x8*)&Xs[(nt * 16 + col) * PITCH + 32 + quad * 8];
        f32x4 av = {0.f, 0.f, 0.f, 0.f};
        av = MFMA16(wva0, xb0, av);
        av = MFMA16(wva1, xb1, av);
#pragma unroll
        for (int r = 0; r < 4; ++r) {
            const int e = wvid * 16 + quad * 4 + r;
            vtws[(bh * NDH + e) * NS + s0 + nt * 16 + col] = f2bf(av[r] + bv[h * NDH + e]);
        }
    }
}

// ---------------------------------------------------------------------------
// Kernel 2: flash attention. Block = (q-tile 64, h, b); 4 waves x 16 q-rows.
// Streams 32 K/V tiles of 64. Online softmax in MFMA C-layout registers.
// P converts C-layout -> A-layout via wave-private LDS round trip.
// ---------------------------------------------------------------------------
__global__ __launch_bounds__(256) void attn_kernel(
    const __bf16* __restrict__ qws, const __bf16* __restrict__ kws,
    const __bf16* __restrict__ vtws, float* __restrict__ out)
{
    const int qt = blockIdx.x, h = blockIdx.y, b = blockIdx.z;
    const int q0 = qt * 64;
    const int tid = threadIdx.x;

    __shared__ __align__(16) __bf16 Qs[64 * PITCH];
    __shared__ __align__(16) __bf16 Ks[64 * PITCH];
    __shared__ __align__(16) __bf16 Vts[64 * PITCH];   // rows = d (0..63), cols = k_local
    __shared__ __align__(16) __bf16 Ps[64 * PITCH];    // wave-private 16-row slabs

    const size_t bh = (size_t)(b * NH + h);
    const int lr = tid >> 2;       // 0..63 load row
    const int sg = tid & 3;        // segment

    // Q tile -> LDS (held for entire kernel)
    {
        const __bf16* src = qws + (bh * NS + q0 + lr) * NDH;
        *(uint4*)&Qs[lr * PITCH + sg * 8]       = *(const uint4*)(src + sg * 8);
        *(uint4*)&Qs[lr * PITCH + (sg + 4) * 8] = *(const uint4*)(src + (sg + 4) * 8);
    }
    __syncthreads();

    const int lane = tid & 63;
    const int wvid = tid >> 6;
    const int col  = lane & 15;
    const int quad = lane >> 4;

    // Q A-fragments, reused across all K tiles
    const bf16x8 qa0 = *(const bf16x8*)&Qs[(wvid * 16 + col) * PITCH + quad * 8];
    const bf16x8 qa1 = *(const bf16x8*)&Qs[(wvid * 16 + col) * PITCH + 32 + quad * 8];

    float m_i[4] = {-INFINITY, -INFINITY, -INFINITY, -INFINITY};
    float l_i[4] = {0.f, 0.f, 0.f, 0.f};
    f32x4 o[4];
#pragma unroll
    for (int dt = 0; dt < 4; ++dt) o[dt] = (f32x4){0.f, 0.f, 0.f, 0.f};

    for (int kt = 0; kt < NS / 64; ++kt) {
        __syncthreads();   // prev iter's MFMAs done before overwriting K/Vt
        {
            const int k0 = kt * 64;
            const __bf16* ksrc = kws + (bh * NS + k0 + lr) * NDH;
            *(uint4*)&Ks[lr * PITCH + sg * 8]       = *(const uint4*)(ksrc + sg * 8);
            *(uint4*)&Ks[lr * PITCH + (sg + 4) * 8] = *(const uint4*)(ksrc + (sg + 4) * 8);
            const __bf16* vsrc = vtws + (bh * NDH + lr) * NS + k0;
            *(uint4*)&Vts[lr * PITCH + sg * 8]       = *(const uint4*)(vsrc + sg * 8);
            *(uint4*)&Vts[lr * PITCH + (sg + 4) * 8] = *(const uint4*)(vsrc + (sg + 4) * 8);
        }
        __syncthreads();

        // ---- scores: S = Q K^T, 16 q-rows x 64 k-cols per wave ----
        f32x4 sc[4];
#pragma unroll
        for (int nt = 0; nt < 4; ++nt) {
            bf16x8 kb0 = *(const bf16x8*)&Ks[(nt * 16 + col) * PITCH + quad * 8];
            bf16x8 kb1 = *(const bf16x8*)&Ks[(nt * 16 + col) * PITCH + 32 + quad * 8];
            f32x4 a = {0.f, 0.f, 0.f, 0.f};
            a = MFMA16(qa0, kb0, a);
            a = MFMA16(qa1, kb1, a);
            sc[nt] = a;
        }
        // scale into log2 domain
#pragma unroll
        for (int nt = 0; nt < 4; ++nt)
#pragma unroll
            for (int r = 0; r < 4; ++r) sc[nt][r] *= SSCALE;

        // ---- online softmax (rows distributed: row = quad*4+r, col = lane&15) ----
        float rowm[4];
#pragma unroll
        for (int r = 0; r < 4; ++r)
            rowm[r] = fmaxf(fmaxf(sc[0][r], sc[1][r]), fmaxf(sc[2][r], sc[3][r]));
#pragma unroll
        for (int msk = 1; msk < 16; msk <<= 1)
#pragma unroll
            for (int r = 0; r < 4; ++r)
                rowm[r] = fmaxf(rowm[r], __shfl_xor(rowm[r], msk, 64));

        float alpha[4];
#pragma unroll
        for (int r = 0; r < 4; ++r) {
            const float mo = m_i[r];
            const float mn = fmaxf(mo, rowm[r]);
            alpha[r] = exp2f(mo - mn);   // 0 on first tile (mo = -inf)
            m_i[r] = mn;
        }

        float rs[4] = {0.f, 0.f, 0.f, 0.f};
        float p[4][4];
#pragma unroll
        for (int nt = 0; nt < 4; ++nt)
#pragma unroll
            for (int r = 0; r < 4; ++r) {
                const float e = exp2f(sc[nt][r] - m_i[r]);
                p[nt][r] = e;
                rs[r] += e;
            }
#pragma unroll
        for (int msk = 1; msk < 16; msk <<= 1)
#pragma unroll
            for (int r = 0; r < 4; ++r)
                rs[r] += __shfl_xor(rs[r], msk, 64);
#pragma unroll
        for (int r = 0; r < 4; ++r) l_i[r] = l_i[r] * alpha[r] + rs[r];

        // ---- P: C-layout -> LDS (wave-private slab) -> A-layout fragments ----
#pragma unroll
        for (int nt = 0; nt < 4; ++nt)
#pragma unroll
            for (int r = 0; r < 4; ++r)
                Ps[(wvid * 16 + quad * 4 + r) * PITCH + nt * 16 + col] = f2bf(p[nt][r]);

        // rescale O
#pragma unroll
        for (int dt = 0; dt < 4; ++dt)
#pragma unroll
            for (int r = 0; r < 4; ++r) o[dt][r] *= alpha[r];

        const bf16x8 pa0 = *(const bf16x8*)&Ps[(wvid * 16 + col) * PITCH + quad * 8];
        const bf16x8 pa1 = *(const bf16x8*)&Ps[(wvid * 16 + col) * PITCH + 32 + quad * 8];
#pragma unroll
        for (int dt = 0; dt < 4; ++dt) {
            bf16x8 vb0 = *(const bf16x8*)&Vts[(dt * 16 + col) * PITCH + quad * 8];
            bf16x8 vb1 = *(const bf16x8*)&Vts[(dt * 16 + col) * PITCH + 32 + quad * 8];
            o[dt] = MFMA16(pa0, vb0, o[dt]);
            o[dt] = MFMA16(pa1, vb1, o[dt]);
        }
    }

    // ---- epilogue: normalize and store fp32 ----
    float inv[4];
#pragma unroll
    for (int r = 0; r < 4; ++r) inv[r] = 1.0f / l_i[r];
#pragma unroll
    for (int dt = 0; dt < 4; ++dt)
#pragma unroll
        for (int r = 0; r < 4; ++r) {
            const int srow = q0 + wvid * 16 + quad * 4 + r;
            out[(size_t)(b * NS + srow) * ND + h * NDH + dt * 16 + col] = o[dt][r] * inv[r];
        }
}

extern "C" void kernel_launch(void* const* d_in, const int* in_sizes, int n_in,
                              void* d_out, int out_size, void* d_ws, size_t ws_size,
                              hipStream_t stream) {
    (void)in_sizes; (void)n_in; (void)out_size; (void)ws_size;
    const float* x  = (const float*)d_in[0];
    const float* wq = (const float*)d_in[1];
    const float* bq = (const float*)d_in[2];
    const float* wk = (const float*)d_in[3];
    const float* bk = (const float*)d_in[4];
    const float* wv = (const float*)d_in[5];
    const float* bv = (const float*)d_in[6];
    float* out = (float*)d_out;

    __bf16* qws  = (__bf16*)d_ws;
    __bf16* kws  = qws + (size_t)NB * NH * NS * NDH;
    __bf16* vtws = kws + (size_t)NB * NH * NS * NDH;

    dim3 grid(NS / 64, NH, NB);
    proj_kernel<<<grid, 256, 0, stream>>>(x, wq, bq, wk, bk, wv, bv, qws, kws, vtws);
    attn_kernel<<<grid, 256, 0, stream>>>(qws, kws, vtws, out);
}

// Round 2
// 191.897 us; speedup vs baseline: 1.4984x; 1.4984x over previous
//
#include <hip/hip_runtime.h>

#define NB 4
#define NS 2048
#define ND 768
#define NH 12
#define NDH 64
#define PITCH 72
#define SSCALE 0.18033688011112043f   // (1/sqrt(64)) * log2(e), folded into Q

typedef __bf16 bf16x8 __attribute__((ext_vector_type(8)));
typedef __bf16 bf16x4 __attribute__((ext_vector_type(4)));
typedef float  f32x4  __attribute__((ext_vector_type(4)));

#define MFMA32(a, b, c) __builtin_amdgcn_mfma_f32_16x16x32_bf16(a, b, c, 0, 0, 0)

// pack two floats -> two bf16 (round-half-up) in one v_perm_b32
__device__ __forceinline__ unsigned packbf(float a, float b) {
    unsigned ua = __builtin_bit_cast(unsigned, a) + 0x8000u;
    unsigned ub = __builtin_bit_cast(unsigned, b) + 0x8000u;
    return __builtin_amdgcn_perm(ub, ua, 0x07060302u);
}

__device__ __forceinline__ bf16x4 cvt4(float4 v) {
    union { unsigned u[2]; bf16x4 b; } r;
    r.u[0] = packbf(v.x, v.y);
    r.u[1] = packbf(v.z, v.w);
    return r.b;
}

__device__ __forceinline__ __bf16 f2bf(float f) {
    unsigned u = __builtin_bit_cast(unsigned, f) + 0x8000u;
    unsigned short s = (unsigned short)(u >> 16);
    return __builtin_bit_cast(__bf16, s);
}

// ---------------------------------------------------------------------------
// Kernel 1: per-head QKV projections (bf16 out). Q pre-scaled by SSCALE.
// Vt stored with column permutation pi(k) = 32*(k>>5) + ((k>>2)&3)*8
//   + ((k>>4)&1)*4 + (k&3)  so that the attention kernel's packed-P registers
//   form a valid 16x16x32 B-fragment with no LDS round trip.
// Block = (2 s-tiles of 64, h, b); weights staged once, reused for both tiles.
// ---------------------------------------------------------------------------
__global__ __launch_bounds__(256, 4) void proj_kernel(
    const float* __restrict__ x,
    const float* __restrict__ wq, const float* __restrict__ bq,
    const float* __restrict__ wk, const float* __restrict__ bk,
    const float* __restrict__ wv, const float* __restrict__ bv,
    __bf16* __restrict__ qws, __bf16* __restrict__ kws, __bf16* __restrict__ vtws)
{
    const int st2 = blockIdx.x, h = blockIdx.y, b = blockIdx.z;
    const int tid = threadIdx.x;

    __shared__ __align__(16) __bf16 Xs[64 * PITCH];
    __shared__ __align__(16) __bf16 Wqs[64 * PITCH];
    __shared__ __align__(16) __bf16 Wks[64 * PITCH];
    __shared__ __align__(16) __bf16 Wvs[64 * PITCH];

    const int r = tid >> 2, q4 = tid & 3;
    {
        const float* wqr = wq + (size_t)(h * NDH + r) * NDH;
        const float* wkr = wk + (size_t)(h * NDH + r) * NDH;
        const float* wvr = wv + (size_t)(h * NDH + r) * NDH;
#pragma unroll
        for (int i = 0; i < 4; ++i) {
            const int cv = q4 * 4 + i;
            *(bf16x4*)&Wqs[r * PITCH + cv * 4] = cvt4(*(const float4*)(wqr + cv * 4));
            *(bf16x4*)&Wks[r * PITCH + cv * 4] = cvt4(*(const float4*)(wkr + cv * 4));
            *(bf16x4*)&Wvs[r * PITCH + cv * 4] = cvt4(*(const float4*)(wvr + cv * 4));
        }
    }

    const int lane = tid & 63, wvid = tid >> 6, col = lane & 15, quad = lane >> 4;
    float biasq[4], biask[4], bvr[4];
#pragma unroll
    for (int nt = 0; nt < 4; ++nt) {
        biasq[nt] = bq[h * NDH + nt * 16 + col];
        biask[nt] = bk[h * NDH + nt * 16 + col];
        bvr[nt]   = bv[h * NDH + wvid * 16 + quad * 4 + nt];
    }
    const size_t bh = (size_t)(b * NH + h);

    for (int sub = 0; sub < 2; ++sub) {
        const int s0 = (st2 * 2 + sub) * 64;
        __syncthreads();   // prev tile's compute done before Xs overwrite
        {
            const float* xrow = x + (size_t)(b * NS + s0 + r) * ND + h * NDH;
#pragma unroll
            for (int i = 0; i < 4; ++i) {
                const int cv = q4 * 4 + i;
                *(bf16x4*)&Xs[r * PITCH + cv * 4] = cvt4(*(const float4*)(xrow + cv * 4));
            }
        }
        __syncthreads();

        const bf16x8 xa0  = *(const bf16x8*)&Xs[(wvid * 16 + col) * PITCH + quad * 8];
        const bf16x8 xa1  = *(const bf16x8*)&Xs[(wvid * 16 + col) * PITCH + 32 + quad * 8];
        const bf16x8 wva0 = *(const bf16x8*)&Wvs[(wvid * 16 + col) * PITCH + quad * 8];
        const bf16x8 wva1 = *(const bf16x8*)&Wvs[(wvid * 16 + col) * PITCH + 32 + quad * 8];

        // Q and K: waves split s (M); n-tiles over e
#pragma unroll
        for (int nt = 0; nt < 4; ++nt) {
            const bf16x8 bq0 = *(const bf16x8*)&Wqs[(nt * 16 + col) * PITCH + quad * 8];
            const bf16x8 bq1 = *(const bf16x8*)&Wqs[(nt * 16 + col) * PITCH + 32 + quad * 8];
            const bf16x8 bk0 = *(const bf16x8*)&Wks[(nt * 16 + col) * PITCH + quad * 8];
            const bf16x8 bk1 = *(const bf16x8*)&Wks[(nt * 16 + col) * PITCH + 32 + quad * 8];
            f32x4 aq = {0.f, 0.f, 0.f, 0.f};
            f32x4 ak = {0.f, 0.f, 0.f, 0.f};
            aq = MFMA32(xa0, bq0, aq);
            aq = MFMA32(xa1, bq1, aq);
            ak = MFMA32(xa0, bk0, ak);
            ak = MFMA32(xa1, bk1, ak);
#pragma unroll
            for (int rr = 0; rr < 4; ++rr) {
                const int srow = s0 + wvid * 16 + quad * 4 + rr;
                qws[(bh * NS + srow) * NDH + nt * 16 + col] = f2bf((aq[rr] + biasq[nt]) * SSCALE);
                kws[(bh * NS + srow) * NDH + nt * 16 + col] = f2bf(ak[rr] + biask[nt]);
            }
        }

        // Vt = Wv . X^T with permuted columns
#pragma unroll
        for (int nt = 0; nt < 4; ++nt) {
            const bf16x8 xb0 = *(const bf16x8*)&Xs[(nt * 16 + col) * PITCH + quad * 8];
            const bf16x8 xb1 = *(const bf16x8*)&Xs[(nt * 16 + col) * PITCH + 32 + quad * 8];
            f32x4 av = {0.f, 0.f, 0.f, 0.f};
            av = MFMA32(wva0, xb0, av);
            av = MFMA32(wva1, xb1, av);
            // k_local = nt*16 + col -> permuted position
            const int pos = ((nt >> 1) << 5) + ((col >> 2) << 3) + ((nt & 1) << 2) + (col & 3);
#pragma unroll
            for (int rr = 0; rr < 4; ++rr) {
                const int e = wvid * 16 + quad * 4 + rr;
                vtws[(bh * NDH + e) * NS + s0 + pos] = f2bf(av[rr] + bvr[rr]);
            }
        }
    }
}

// ---------------------------------------------------------------------------
// Kernel 2: flash attention, S^T formulation.
//  S^T = K·Q^T  (A-frag = K rows, B-frag = Q rows) -> C rows = k, cols = q.
//  Softmax over k: 15 in-lane ops + 2 shuffles; per-lane scalar m/l/alpha.
//  Packed P^T registers are directly the PV B-fragment (Vt columns were
//  permuted at projection time to match). O^T = Vt·P^T accumulated in C-layout.
//  K/Vt staging register-pipelined: tile t+1 loads in flight during compute t.
// ---------------------------------------------------------------------------
__global__ __launch_bounds__(256, 4) void attn_kernel(
    const __bf16* __restrict__ qws, const __bf16* __restrict__ kws,
    const __bf16* __restrict__ vtws, float* __restrict__ out)
{
    const int qt = blockIdx.x, h = blockIdx.y, b = blockIdx.z;
    const int q0 = qt * 64;
    const int tid = threadIdx.x;

    __shared__ __align__(16) __bf16 Qs[64 * PITCH];
    __shared__ __align__(16) __bf16 Ks[64 * PITCH];
    __shared__ __align__(16) __bf16 Vts[64 * PITCH];

    const size_t bh = (size_t)(b * NH + h);
    const int lr = tid >> 2, sg = tid & 3;

    // Q tile -> LDS (held for whole kernel)
    {
        const __bf16* src = qws + (bh * NS + q0 + lr) * NDH;
        *(uint4*)&Qs[lr * PITCH + sg * 8]       = *(const uint4*)(src + sg * 8);
        *(uint4*)&Qs[lr * PITCH + (sg + 4) * 8] = *(const uint4*)(src + (sg + 4) * 8);
    }

    const __bf16* kbase = kws + bh * NS * NDH;
    const __bf16* vbase = vtws + (bh * NDH + lr) * NS;

    // preload tile 0 into registers
    uint4 kr0, kr1, vr0, vr1;
    {
        const __bf16* kp = kbase + (size_t)lr * NDH;
        kr0 = *(const uint4*)(kp + sg * 8);
        kr1 = *(const uint4*)(kp + (sg + 4) * 8);
        vr0 = *(const uint4*)(vbase + sg * 8);
        vr1 = *(const uint4*)(vbase + (sg + 4) * 8);
    }

    __syncthreads();   // Qs visible

    const int lane = tid & 63, w = tid >> 6, col = lane & 15, quad = lane >> 4;
    // Q B-fragments (q = w*16+col), reused across all K tiles
    const bf16x8 qb0 = *(const bf16x8*)&Qs[(w * 16 + col) * PITCH + quad * 8];
    const bf16x8 qb1 = *(const bf16x8*)&Qs[(w * 16 + col) * PITCH + 32 + quad * 8];

    float m = -__builtin_inff();
    float l = 0.f;
    f32x4 o[4];
#pragma unroll
    for (int dt = 0; dt < 4; ++dt) o[dt] = (f32x4){0.f, 0.f, 0.f, 0.f};

    for (int kt = 0; kt < NS / 64; ++kt) {
        __syncthreads();   // prev tile's LDS consumers done
        *(uint4*)&Ks[lr * PITCH + sg * 8]        = kr0;
        *(uint4*)&Ks[lr * PITCH + (sg + 4) * 8]  = kr1;
        *(uint4*)&Vts[lr * PITCH + sg * 8]       = vr0;
        *(uint4*)&Vts[lr * PITCH + (sg + 4) * 8] = vr1;
        if (kt + 1 < NS / 64) {
            const int k0n = (kt + 1) * 64;
            const __bf16* kp = kbase + (size_t)(k0n + lr) * NDH;
            kr0 = *(const uint4*)(kp + sg * 8);
            kr1 = *(const uint4*)(kp + (sg + 4) * 8);
            vr0 = *(const uint4*)(vbase + k0n + sg * 8);
            vr1 = *(const uint4*)(vbase + k0n + (sg + 4) * 8);
        }
        __syncthreads();   // staging visible

        // ---- S^T tile: rows k (4 m-tiles), cols q (this wave's 16) ----
        f32x4 sc[4];
#pragma unroll
        for (int mt = 0; mt < 4; ++mt) {
            const bf16x8 ka0 = *(const bf16x8*)&Ks[(mt * 16 + col) * PITCH + quad * 8];
            const bf16x8 ka1 = *(const bf16x8*)&Ks[(mt * 16 + col) * PITCH + 32 + quad * 8];
            f32x4 a = {0.f, 0.f, 0.f, 0.f};
            a = MFMA32(ka0, qb0, a);
            a = MFMA32(ka1, qb1, a);
            sc[mt] = a;   // element [k = mt*16 + quad*4 + r][q = col], log2-domain
        }

        // ---- online softmax over k (in-lane 16 + butterfly over quads) ----
        float rowm = sc[0][0];
#pragma unroll
        for (int mt = 0; mt < 4; ++mt)
#pragma unroll
            for (int rr = 0; rr < 4; ++rr) rowm = fmaxf(rowm, sc[mt][rr]);
        rowm = fmaxf(rowm, __shfl_xor(rowm, 16, 64));
        rowm = fmaxf(rowm, __shfl_xor(rowm, 32, 64));

        const float mn = fmaxf(m, rowm);
        const float alpha = __builtin_amdgcn_exp2f(m - mn);   // 0 on first tile
        m = mn;

        float rs = 0.f;
        unsigned pu[8];
#pragma unroll
        for (int mt = 0; mt < 4; ++mt) {
            const float p0 = __builtin_amdgcn_exp2f(sc[mt][0] - mn);
            const float p1 = __builtin_amdgcn_exp2f(sc[mt][1] - mn);
            const float p2 = __builtin_amdgcn_exp2f(sc[mt][2] - mn);
            const float p3 = __builtin_amdgcn_exp2f(sc[mt][3] - mn);
            rs += (p0 + p1) + (p2 + p3);
            pu[mt * 2]     = packbf(p0, p1);
            pu[mt * 2 + 1] = packbf(p2, p3);
        }
        rs += __shfl_xor(rs, 16, 64);
        rs += __shfl_xor(rs, 32, 64);
        l = l * alpha + rs;

#pragma unroll
        for (int dt = 0; dt < 4; ++dt)
#pragma unroll
            for (int rr = 0; rr < 4; ++rr) o[dt][rr] *= alpha;

        // packed P^T registers ARE the PV B-fragments (Vt columns permuted)
        union { unsigned u[4]; bf16x8 v; } pb0, pb1;
        pb0.u[0] = pu[0]; pb0.u[1] = pu[1]; pb0.u[2] = pu[2]; pb0.u[3] = pu[3];
        pb1.u[0] = pu[4]; pb1.u[1] = pu[5]; pb1.u[2] = pu[6]; pb1.u[3] = pu[7];

        // ---- O^T += Vt . P^T ----
#pragma unroll
        for (int dt = 0; dt < 4; ++dt) {
            const bf16x8 va0 = *(const bf16x8*)&Vts[(dt * 16 + col) * PITCH + quad * 8];
            const bf16x8 va1 = *(const bf16x8*)&Vts[(dt * 16 + col) * PITCH + 32 + quad * 8];
            o[dt] = MFMA32(va0, pb0.v, o[dt]);
            o[dt] = MFMA32(va1, pb1.v, o[dt]);
        }
    }

    // ---- epilogue: normalize, store fp32 as float4 (contiguous in d) ----
    const float inv = 1.0f / l;
#pragma unroll
    for (int dt = 0; dt < 4; ++dt) {
        float4 val;
        val.x = o[dt][0] * inv;
        val.y = o[dt][1] * inv;
        val.z = o[dt][2] * inv;
        val.w = o[dt][3] * inv;
        *(float4*)&out[(size_t)(b * NS + q0 + w * 16 + col) * ND + h * NDH + dt * 16 + quad * 4] = val;
    }
}

extern "C" void kernel_launch(void* const* d_in, const int* in_sizes, int n_in,
                              void* d_out, int out_size, void* d_ws, size_t ws_size,
                              hipStream_t stream) {
    (void)in_sizes; (void)n_in; (void)out_size; (void)ws_size;
    const float* x  = (const float*)d_in[0];
    const float* wq = (const float*)d_in[1];
    const float* bq = (const float*)d_in[2];
    const float* wk = (const float*)d_in[3];
    const float* bk = (const float*)d_in[4];
    const float* wv = (const float*)d_in[5];
    const float* bv = (const float*)d_in[6];
    float* out = (float*)d_out;

    __bf16* qws  = (__bf16*)d_ws;
    __bf16* kws  = qws + (size_t)NB * NH * NS * NDH;
    __bf16* vtws = kws + (size_t)NB * NH * NS * NDH;

    dim3 pgrid(NS / 128, NH, NB);
    proj_kernel<<<pgrid, 256, 0, stream>>>(x, wq, bq, wk, bk, wv, bv, qws, kws, vtws);
    dim3 agrid(NS / 64, NH, NB);
    attn_kernel<<<agrid, 256, 0, stream>>>(qws, kws, vtws, out);
}